// Round 11
// baseline (286.042 us; speedup 1.0000x reference)
//
#include <hip/hip_runtime.h>
#include <math.h>
#include <stdint.h>

#define D 128          // feature dim (d_in = d_h = 128)
#define SCAN_CHUNK 2048
#define LDA 136        // LDS row stride in shorts (+8 pad: 16-way -> 2-way bank conflict)

typedef __attribute__((ext_vector_type(8))) short v8s;   // 8 bf16 (4 VGPRs)
typedef __attribute__((ext_vector_type(4))) float v4f;   // MFMA accumulator

// bf16 round-to-nearest-even
static __device__ __forceinline__ uint16_t f2bf(float f) {
    uint32_t u = __float_as_uint(f);
    u = (u + 0x7fff + ((u >> 16) & 1)) >> 16;
    return (uint16_t)u;
}
static __device__ __forceinline__ float bf2f(uint16_t h) { return __uint_as_float((uint32_t)h << 16); }
static __device__ __forceinline__ float bf_lo(uint32_t u) { return __uint_as_float(u << 16); }
static __device__ __forceinline__ float bf_hi(uint32_t u) { return __uint_as_float(u & 0xffff0000u); }

// ---------------- count + W-pack (fused, independent work) ----------------
// pack layout: frag f = kstep*8 + tile (0..31); element ((f*64)+lane)*8 + j
// maps to W[k = kstep*32 + (lane>>4)*8 + j][nn = tile*16 + (lane&15)]

__global__ void countpack_kernel(const int* __restrict__ col, int* __restrict__ cnt, int E,
                                 const float* __restrict__ W1, const float* __restrict__ W2,
                                 uint16_t* __restrict__ Wh, uint16_t* __restrict__ Wl) {
    int tid = blockIdx.x * blockDim.x + threadIdx.x;
    if (tid < 2 * 16384) {
        int layer = tid >> 14;
        int li = tid & 16383;
        int j = li & 7, lane = (li >> 3) & 63, f = li >> 9;
        int kstep = f >> 3, tile = f & 7;
        int k = kstep * 32 + ((lane >> 4) * 8) + j;
        int nn = tile * 16 + (lane & 15);
        const float* W = layer ? W2 : W1;
        float v = W[k * 128 + nn];
        uint16_t h = f2bf(v);
        Wh[tid] = h;
        Wl[tid] = f2bf(v - bf2f(h));
    }
    if (tid < E) atomicAdd(&cnt[col[tid]], 1);
}

// ---------------- single-kernel scan: base via redundant per-block prefix sum ----------
// block b sums cnt[0 .. b*CHUNK) itself (cnt is 200 KB, L2-hot), then local scan.
// fused: dinv computation + curs zeroing.

__global__ __launch_bounds__(256) void scan_kernel(const int* __restrict__ cnt,
                                                   int* __restrict__ offs,
                                                   float* __restrict__ dinv,
                                                   int* __restrict__ curs,
                                                   int n, int nbScan) {
    __shared__ int stage[SCAN_CHUNK];
    __shared__ int res[SCAN_CHUNK];
    __shared__ int tsum[256];
    __shared__ int red[4];
    int b = blockIdx.x, t = threadIdx.x;
    int pre = b * SCAN_CHUNK;

    // redundant prefix: sum of all counts before this chunk
    int s = 0;
    for (int i = t; i < pre; i += 256) s += cnt[i];
#pragma unroll
    for (int off = 32; off > 0; off >>= 1) s += __shfl_xor(s, off, 64);
    if ((t & 63) == 0) red[t >> 6] = s;

    // load own chunk (+ fused dinv write + curs zero)
#pragma unroll
    for (int k = 0; k < SCAN_CHUNK / 256; k++) {
        int i = pre + k * 256 + t;
        int c = (i < n) ? cnt[i] : 0;
        stage[k * 256 + t] = c;
        if (i < n) {
            dinv[i] = rsqrtf((float)c + 1.0f);
            curs[i] = 0;
        }
    }
    __syncthreads();
    int bbase = red[0] + red[1] + red[2] + red[3];

    int my = 0;
#pragma unroll
    for (int j = 0; j < 8; j++) my += stage[t * 8 + j];
    tsum[t] = my;
    __syncthreads();
    for (int off = 1; off < 256; off <<= 1) {
        int v = (t >= off) ? tsum[t - off] : 0;
        __syncthreads();
        tsum[t] += v;
        __syncthreads();
    }
    int run = tsum[t] - my + bbase;
#pragma unroll
    for (int j = 0; j < 8; j++) {
        res[t * 8 + j] = run;
        run += stage[t * 8 + j];
    }
    __syncthreads();
#pragma unroll
    for (int k = 0; k < SCAN_CHUNK / 256; k++) {
        int i = pre + k * 256 + t;
        if (i < n) offs[i] = res[k * 256 + t];
    }
    if (b == nbScan - 1 && t == 255) offs[n] = bbase + tsum[255];
}

__global__ void fill_kernel(const int* row, const int* col, const int* offs,
                            int* curs, int* adj, int E) {
    int e = blockIdx.x * blockDim.x + threadIdx.x;
    if (e < E) {
        int c = col[e];
        int p = atomicAdd(&curs[c], 1);
        adj[offs[c] + p] = row[e];
    }
}

// ---------------- MFMA GEMM: xwb[i,:] = bf16( dinv[i] * (A[i,:] @ W) ) ----------------
// split-bf16 (Markidis): A = Ah + Al, W = Wh + Wl; A@W ~= Ah@Wh + Ah@Wl + Al@Wh

__global__ __launch_bounds__(256) void gemm_mfma_kernel(const float* __restrict__ A,
                                                        const uint16_t* __restrict__ Wph,
                                                        const uint16_t* __restrict__ Wpl,
                                                        const float* __restrict__ dinv,
                                                        uint16_t* __restrict__ Cb, int M) {
    __shared__ uint16_t Ah[64][LDA];
    __shared__ uint16_t Al[64][LDA];
    int t = threadIdx.x;
    int base_row = blockIdx.x * 64;

#pragma unroll
    for (int kk = 0; kk < 8; kk++) {
        int idx = kk * 256 + t;
        int r = idx >> 5;
        int c4 = idx & 31;
        int gr = base_row + r;
        float4 f = (gr < M) ? *(const float4*)(A + (size_t)gr * D + c4 * 4)
                            : make_float4(0.f, 0.f, 0.f, 0.f);
        uint16_t h0 = f2bf(f.x), h1 = f2bf(f.y), h2 = f2bf(f.z), h3 = f2bf(f.w);
        uint16_t l0 = f2bf(f.x - bf2f(h0)), l1 = f2bf(f.y - bf2f(h1));
        uint16_t l2 = f2bf(f.z - bf2f(h2)), l3 = f2bf(f.w - bf2f(h3));
        *(ushort4*)&Ah[r][c4 * 4] = make_ushort4(h0, h1, h2, h3);
        *(ushort4*)&Al[r][c4 * 4] = make_ushort4(l0, l1, l2, l3);
    }
    __syncthreads();

    int lane = t & 63, w = t >> 6;
    int m_l = lane & 15, quad = lane >> 4;
    int arow = w * 16 + m_l;

    v4f acc[8];
#pragma unroll
    for (int i = 0; i < 8; i++) acc[i] = (v4f){0.f, 0.f, 0.f, 0.f};

#pragma unroll
    for (int ks = 0; ks < 4; ks++) {
        v8s ah = *(const v8s*)&Ah[arow][ks * 32 + quad * 8];
        v8s al = *(const v8s*)&Al[arow][ks * 32 + quad * 8];
#pragma unroll
        for (int ti = 0; ti < 8; ti++) {
            int f = ks * 8 + ti;
            v8s bh = *(const v8s*)(Wph + ((size_t)(f * 64 + lane)) * 8);
            v8s bl = *(const v8s*)(Wpl + ((size_t)(f * 64 + lane)) * 8);
            acc[ti] = __builtin_amdgcn_mfma_f32_16x16x32_bf16(al, bh, acc[ti], 0, 0, 0);
            acc[ti] = __builtin_amdgcn_mfma_f32_16x16x32_bf16(ah, bl, acc[ti], 0, 0, 0);
            acc[ti] = __builtin_amdgcn_mfma_f32_16x16x32_bf16(ah, bh, acc[ti], 0, 0, 0);
        }
    }

    int rbase = base_row + w * 16 + quad * 4;
#pragma unroll
    for (int reg = 0; reg < 4; reg++) {
        int gr = rbase + reg;
        if (gr < M) {
            float di = dinv[gr];
#pragma unroll
            for (int ti = 0; ti < 8; ti++) {
                Cb[(size_t)gr * D + ti * 16 + m_l] = f2bf(di * acc[ti][reg]);
            }
        }
    }
}

// ---------------- aggregation: one wave per node ----------------
// wave-uniform adj indices -> scalar loads; 8 independent row gathers in flight.
// epilogue kept thin (no wave reductions) — r6/r10 lesson.

__global__ __launch_bounds__(256) void agg_kernel(const uint32_t* __restrict__ xwb,
                                                  const int* __restrict__ adj,
                                                  const int* __restrict__ offs,
                                                  const float* __restrict__ dinv,
                                                  const float* __restrict__ bias,
                                                  float* __restrict__ hout, int n) {
    int wave = (int)((blockIdx.x * (size_t)blockDim.x + threadIdx.x) >> 6);
    int lane = threadIdx.x & 63;
    if (wave >= n) return;
    int i = wave;
    uint32_t su = xwb[(size_t)i * (D / 2) + lane];
    float acc0 = bf_lo(su);
    float acc1 = bf_hi(su);
    int s = offs[i], e = offs[i + 1];
    int j = s;
    for (; j + 7 < e; j += 8) {
        int r0 = adj[j],     r1 = adj[j + 1], r2 = adj[j + 2], r3 = adj[j + 3];
        int r4 = adj[j + 4], r5 = adj[j + 5], r6 = adj[j + 6], r7 = adj[j + 7];
        uint32_t u0 = xwb[(size_t)r0 * (D / 2) + lane];
        uint32_t u1 = xwb[(size_t)r1 * (D / 2) + lane];
        uint32_t u2 = xwb[(size_t)r2 * (D / 2) + lane];
        uint32_t u3 = xwb[(size_t)r3 * (D / 2) + lane];
        uint32_t u4 = xwb[(size_t)r4 * (D / 2) + lane];
        uint32_t u5 = xwb[(size_t)r5 * (D / 2) + lane];
        uint32_t u6 = xwb[(size_t)r6 * (D / 2) + lane];
        uint32_t u7 = xwb[(size_t)r7 * (D / 2) + lane];
        acc0 += bf_lo(u0); acc1 += bf_hi(u0);
        acc0 += bf_lo(u1); acc1 += bf_hi(u1);
        acc0 += bf_lo(u2); acc1 += bf_hi(u2);
        acc0 += bf_lo(u3); acc1 += bf_hi(u3);
        acc0 += bf_lo(u4); acc1 += bf_hi(u4);
        acc0 += bf_lo(u5); acc1 += bf_hi(u5);
        acc0 += bf_lo(u6); acc1 += bf_hi(u6);
        acc0 += bf_lo(u7); acc1 += bf_hi(u7);
    }
    for (; j + 3 < e; j += 4) {
        int r0 = adj[j], r1 = adj[j + 1], r2 = adj[j + 2], r3 = adj[j + 3];
        uint32_t u0 = xwb[(size_t)r0 * (D / 2) + lane];
        uint32_t u1 = xwb[(size_t)r1 * (D / 2) + lane];
        uint32_t u2 = xwb[(size_t)r2 * (D / 2) + lane];
        uint32_t u3 = xwb[(size_t)r3 * (D / 2) + lane];
        acc0 += bf_lo(u0); acc1 += bf_hi(u0);
        acc0 += bf_lo(u1); acc1 += bf_hi(u1);
        acc0 += bf_lo(u2); acc1 += bf_hi(u2);
        acc0 += bf_lo(u3); acc1 += bf_hi(u3);
    }
    for (; j < e; j++) {
        int r = adj[j];
        uint32_t u = xwb[(size_t)r * (D / 2) + lane];
        acc0 += bf_lo(u); acc1 += bf_hi(u);
    }
    float di = dinv[i];
    float2 bv = ((const float2*)bias)[lane];
    float o0 = fmaxf(fmaf(di, acc0, bv.x), 0.f);
    float o1 = fmaxf(fmaf(di, acc1, bv.y), 0.f);
    ((float2*)(hout + (size_t)i * D))[lane] = make_float2(o0, o1);
}

// ---------------- edge-classifier precompute (standalone, epilogue-thin agg) ----------

__global__ __launch_bounds__(256) void pq_kernel(const float* __restrict__ h,
                                                 const float* __restrict__ Wfc,
                                                 const float* __restrict__ bfc,
                                                 float* __restrict__ P1,
                                                 float* __restrict__ P2, int n) {
    int i = blockIdx.x * blockDim.x + threadIdx.x;
    if (i >= n) return;
    const float4* hr = (const float4*)(h + (size_t)i * D);
    const float4* W4 = (const float4*)Wfc;
    float p0 = bfc[0], p1 = bfc[1], p2 = bfc[2], p3 = bfc[3];
    float q0 = 0.f, q1 = 0.f, q2 = 0.f, q3 = 0.f;
#pragma unroll 8
    for (int kk = 0; kk < 32; kk++) {
        float4 f = hr[kk];
#pragma unroll
        for (int j = 0; j < 4; j++) {
            float fv = (j == 0) ? f.x : (j == 1) ? f.y : (j == 2) ? f.z : f.w;
            int k = kk * 4 + j;
            float4 w1 = W4[k];
            float4 w2 = W4[128 + k];
            p0 = fmaf(fv, w1.x, p0); p1 = fmaf(fv, w1.y, p1);
            p2 = fmaf(fv, w1.z, p2); p3 = fmaf(fv, w1.w, p3);
            q0 = fmaf(fv, w2.x, q0); q1 = fmaf(fv, w2.y, q1);
            q2 = fmaf(fv, w2.z, q2); q3 = fmaf(fv, w2.w, q3);
        }
    }
    ((float4*)P1)[i] = make_float4(p0, p1, p2, p3);
    ((float4*)P2)[i] = make_float4(q0, q1, q2, q3);
}

// ---------------- edge classifier: one THREAD per edge ----------------

__global__ __launch_bounds__(256) void edge2_kernel(const int* __restrict__ row,
                                                    const int* __restrict__ col,
                                                    const float* __restrict__ P1,
                                                    const float* __restrict__ P2,
                                                    float* __restrict__ out, int E) {
    int e = blockIdx.x * blockDim.x + threadIdx.x;
    if (e >= E) return;
    int r = row[e], c = col[e];
    float4 a = ((const float4*)P1)[r];
    float4 b = ((const float4*)P2)[c];
    float sx = a.x + b.x, sy = a.y + b.y, sz = a.z + b.z, sw = a.w + b.w;
    float m = fmaxf(fmaxf(sx, sy), fmaxf(sz, sw));
    float e0 = expf(sx - m), e1 = expf(sy - m), e2 = expf(sz - m), e3 = expf(sw - m);
    float lse = m + logf(e0 + e1 + e2 + e3);
    *(float4*)(out + (size_t)e * 4) = make_float4(sx - lse, sy - lse, sz - lse, sw - lse);
}

// ---------------- launch ----------------

extern "C" void kernel_launch(void* const* d_in, const int* in_sizes, int n_in,
                              void* d_out, int out_size, void* d_ws, size_t ws_size,
                              hipStream_t stream) {
    const float* x   = (const float*)d_in[0];
    const int*   ei  = (const int*)d_in[1];
    const float* W1  = (const float*)d_in[2];
    const float* b1  = (const float*)d_in[3];
    const float* W2  = (const float*)d_in[4];
    const float* b2  = (const float*)d_in[5];
    const float* Wfc = (const float*)d_in[6];
    const float* bfc = (const float*)d_in[7];
    float* out = (float*)d_out;

    int n = in_sizes[0] / D;        // 50000
    int E = in_sizes[1] / 2;        // 600000
    const int* row = ei;            // edge_index[0]
    const int* col = ei + E;        // edge_index[1]
    int nbScan = (n + SCAN_CHUNK - 1) / SCAN_CHUNK;   // 25

    // workspace layout (all segments 16B-aligned)
    uint16_t* xwb  = (uint16_t*)d_ws;                    // n*D bf16 (dinv-prescaled xW)
    float*    h    = (float*)(xwb + (size_t)n * D);      // n*D f32
    int*      cnt  = (int*)(h + (size_t)n * D);          // n
    int*      curs = cnt + n;                            // n (zeroed inside scan_kernel)
    int*      offs = curs + n;                           // n+4
    int*      adj  = offs + (n + 4);                     // E
    float*    dinv = (float*)(adj + E);                  // n
    uint16_t* Wph  = (uint16_t*)(dinv + n);              // 2*16384 (layer-major)
    uint16_t* Wpl  = Wph + 2 * 16384;                    // 2*16384
    float*    P1   = (float*)(Wpl + 2 * 16384);          // n*4
    float*    P2   = P1 + (size_t)n * 4;                 // n*4

    int nb_n = (n + 255) / 256;
    int nb_e = (E + 255) / 256;

    // CSR build
    hipMemsetAsync(cnt, 0, (size_t)n * sizeof(int), stream);
    countpack_kernel<<<nb_e, 256, 0, stream>>>(col, cnt, E, W1, W2, Wph, Wpl);
    scan_kernel<<<nbScan, 256, 0, stream>>>(cnt, offs, dinv, curs, n, nbScan);
    fill_kernel<<<nb_e, 256, 0, stream>>>(row, col, offs, curs, adj, E);

    int nbG = (n + 63) / 64;

    // layer 1
    gemm_mfma_kernel<<<nbG, 256, 0, stream>>>(x, Wph, Wpl, dinv, xwb, n);
    agg_kernel<<<(n + 3) / 4, 256, 0, stream>>>((const uint32_t*)xwb, adj, offs, dinv, b1, h, n);
    // layer 2
    gemm_mfma_kernel<<<nbG, 256, 0, stream>>>(h, Wph + 16384, Wpl + 16384, dinv, xwb, n);
    agg_kernel<<<(n + 3) / 4, 256, 0, stream>>>((const uint32_t*)xwb, adj, offs, dinv, b2, h, n);

    // edge classifier
    pq_kernel<<<nb_n, 256, 0, stream>>>(h, Wfc, bfc, P1, P2, n);
    edge2_kernel<<<nb_e, 256, 0, stream>>>(row, col, P1, P2, out, E);
}

// Round 12
// 265.243 us; speedup vs baseline: 1.0784x; 1.0784x over previous
//
#include <hip/hip_runtime.h>
#include <math.h>
#include <stdint.h>

#define D 128          // feature dim (d_in = d_h = 128)
#define SCAN_CHUNK 2048
#define LDA 136        // LDS row stride in shorts (+8 pad: 16-way -> 2-way bank conflict)

typedef __attribute__((ext_vector_type(8))) short v8s;   // 8 bf16 (4 VGPRs)
typedef __attribute__((ext_vector_type(4))) float v4f;   // MFMA accumulator

// bf16 round-to-nearest-even
static __device__ __forceinline__ uint16_t f2bf(float f) {
    uint32_t u = __float_as_uint(f);
    u = (u + 0x7fff + ((u >> 16) & 1)) >> 16;
    return (uint16_t)u;
}
static __device__ __forceinline__ float bf2f(uint16_t h) { return __uint_as_float((uint32_t)h << 16); }
static __device__ __forceinline__ float bf_lo(uint32_t u) { return __uint_as_float(u << 16); }
static __device__ __forceinline__ float bf_hi(uint32_t u) { return __uint_as_float(u & 0xffff0000u); }

// ---------------- count + W-pack (fused, independent work) ----------------

__global__ void countpack_kernel(const int* __restrict__ col, int* __restrict__ cnt, int E,
                                 const float* __restrict__ W1, const float* __restrict__ W2,
                                 uint16_t* __restrict__ Wh, uint16_t* __restrict__ Wl) {
    int tid = blockIdx.x * blockDim.x + threadIdx.x;
    if (tid < 2 * 16384) {
        int layer = tid >> 14;
        int li = tid & 16383;
        int j = li & 7, lane = (li >> 3) & 63, f = li >> 9;
        int kstep = f >> 3, tile = f & 7;
        int k = kstep * 32 + ((lane >> 4) * 8) + j;
        int nn = tile * 16 + (lane & 15);
        const float* W = layer ? W2 : W1;
        float v = W[k * 128 + nn];
        uint16_t h = f2bf(v);
        Wh[tid] = h;
        Wl[tid] = f2bf(v - bf2f(h));
    }
    if (tid < E) atomicAdd(&cnt[col[tid]], 1);
}

// ---------------- scan phase A: per-chunk sums (+ fused dinv) ----------------

__global__ __launch_bounds__(256) void scanA_kernel(const int* __restrict__ cnt,
                                                    int* __restrict__ bsum,
                                                    float* __restrict__ dinv, int n) {
    __shared__ int wsum[4];
    int b = blockIdx.x, t = threadIdx.x;
    int base = b * SCAN_CHUNK;
    int s = 0;
#pragma unroll
    for (int k = 0; k < SCAN_CHUNK / 256; k++) {
        int i = base + k * 256 + t;
        if (i < n) {
            int c = cnt[i];
            s += c;
            dinv[i] = rsqrtf((float)c + 1.0f);
        }
    }
#pragma unroll
    for (int off = 32; off > 0; off >>= 1) s += __shfl_xor(s, off, 64);
    if ((t & 63) == 0) wsum[t >> 6] = s;
    __syncthreads();
    if (t == 0) bsum[b] = wsum[0] + wsum[1] + wsum[2] + wsum[3];
}

// ---------------- scan phase C: local exclusive scan, block bases inlined ----------------

__global__ __launch_bounds__(256) void scanC_kernel(const int* __restrict__ cnt,
                                                    const int* __restrict__ bsum,
                                                    int* __restrict__ offs, int n, int nb) {
    __shared__ int stage[SCAN_CHUNK];
    __shared__ int res[SCAN_CHUNK];
    __shared__ int tsum[256];
    __shared__ int sb[64];
    int b = blockIdx.x, t = threadIdx.x;
    if (t < 64) {
        int v = (t < nb) ? bsum[t] : 0;
        int inc = v;
#pragma unroll
        for (int off = 1; off < 64; off <<= 1) {
            int u = __shfl_up(inc, off, 64);
            if (t >= off) inc += u;
        }
        sb[t] = inc;
    }
    int base = b * SCAN_CHUNK;
#pragma unroll
    for (int k = 0; k < SCAN_CHUNK / 256; k++) {
        int i = base + k * 256 + t;
        stage[k * 256 + t] = (i < n) ? cnt[i] : 0;
    }
    __syncthreads();
    int my = 0;
#pragma unroll
    for (int j = 0; j < 8; j++) my += stage[t * 8 + j];
    tsum[t] = my;
    __syncthreads();
    for (int off = 1; off < 256; off <<= 1) {
        int v = (t >= off) ? tsum[t - off] : 0;
        __syncthreads();
        tsum[t] += v;
        __syncthreads();
    }
    int bbase = (b == 0) ? 0 : sb[b - 1];
    int run = tsum[t] - my + bbase;
#pragma unroll
    for (int j = 0; j < 8; j++) {
        res[t * 8 + j] = run;
        run += stage[t * 8 + j];
    }
    __syncthreads();
#pragma unroll
    for (int k = 0; k < SCAN_CHUNK / 256; k++) {
        int i = base + k * 256 + t;
        if (i < n) offs[i] = res[k * 256 + t];
    }
    if (b == gridDim.x - 1 && t == 0) offs[n] = sb[nb - 1];
}

__global__ void fill_kernel(const int* row, const int* col, const int* offs,
                            int* curs, int* adj, int E) {
    int e = blockIdx.x * blockDim.x + threadIdx.x;
    if (e < E) {
        int c = col[e];
        int p = atomicAdd(&curs[c], 1);
        adj[offs[c] + p] = row[e];
    }
}

// ---------------- MFMA GEMM: xwb[i,:] = bf16( dinv[i] * (A[i,:] @ W) ) ----------------

__global__ __launch_bounds__(256) void gemm_mfma_kernel(const float* __restrict__ A,
                                                        const uint16_t* __restrict__ Wph,
                                                        const uint16_t* __restrict__ Wpl,
                                                        const float* __restrict__ dinv,
                                                        uint16_t* __restrict__ Cb, int M) {
    __shared__ uint16_t Ah[64][LDA];
    __shared__ uint16_t Al[64][LDA];
    int t = threadIdx.x;
    int base_row = blockIdx.x * 64;

#pragma unroll
    for (int kk = 0; kk < 8; kk++) {
        int idx = kk * 256 + t;
        int r = idx >> 5;
        int c4 = idx & 31;
        int gr = base_row + r;
        float4 f = (gr < M) ? *(const float4*)(A + (size_t)gr * D + c4 * 4)
                            : make_float4(0.f, 0.f, 0.f, 0.f);
        uint16_t h0 = f2bf(f.x), h1 = f2bf(f.y), h2 = f2bf(f.z), h3 = f2bf(f.w);
        uint16_t l0 = f2bf(f.x - bf2f(h0)), l1 = f2bf(f.y - bf2f(h1));
        uint16_t l2 = f2bf(f.z - bf2f(h2)), l3 = f2bf(f.w - bf2f(h3));
        *(ushort4*)&Ah[r][c4 * 4] = make_ushort4(h0, h1, h2, h3);
        *(ushort4*)&Al[r][c4 * 4] = make_ushort4(l0, l1, l2, l3);
    }
    __syncthreads();

    int lane = t & 63, w = t >> 6;
    int m_l = lane & 15, quad = lane >> 4;
    int arow = w * 16 + m_l;

    v4f acc[8];
#pragma unroll
    for (int i = 0; i < 8; i++) acc[i] = (v4f){0.f, 0.f, 0.f, 0.f};

#pragma unroll
    for (int ks = 0; ks < 4; ks++) {
        v8s ah = *(const v8s*)&Ah[arow][ks * 32 + quad * 8];
        v8s al = *(const v8s*)&Al[arow][ks * 32 + quad * 8];
#pragma unroll
        for (int ti = 0; ti < 8; ti++) {
            int f = ks * 8 + ti;
            v8s bh = *(const v8s*)(Wph + ((size_t)(f * 64 + lane)) * 8);
            v8s bl = *(const v8s*)(Wpl + ((size_t)(f * 64 + lane)) * 8);
            acc[ti] = __builtin_amdgcn_mfma_f32_16x16x32_bf16(al, bh, acc[ti], 0, 0, 0);
            acc[ti] = __builtin_amdgcn_mfma_f32_16x16x32_bf16(ah, bl, acc[ti], 0, 0, 0);
            acc[ti] = __builtin_amdgcn_mfma_f32_16x16x32_bf16(ah, bh, acc[ti], 0, 0, 0);
        }
    }

    int rbase = base_row + w * 16 + quad * 4;
#pragma unroll
    for (int reg = 0; reg < 4; reg++) {
        int gr = rbase + reg;
        if (gr < M) {
            float di = dinv[gr];
#pragma unroll
            for (int ti = 0; ti < 8; ti++) {
                Cb[(size_t)gr * D + ti * 16 + m_l] = f2bf(di * acc[ti][reg]);
            }
        }
    }
}

// ---------------- aggregation: one wave per node, half-wave uint2 gather ----------------
// 2 rows per VMEM instruction (lanes 0-31 row A, 32-63 row B), unroll 8 => 16 rows
// in flight per wave (2x MLP vs r7). adj indices stay wave-uniform (scalar loads);
// per-half row selection is a register cndmask, NOT a divergent adj index (r6 lesson).
// Virtual edge list: v in [0, deg] with row(v) = v<deg ? adj[s+v] : i  (self last).
// Epilogue: 4 shfl_xor(32) only (thin — r6/r10 lesson).

__global__ __launch_bounds__(256) void agg_kernel(const uint16_t* __restrict__ xwb,
                                                  const int* __restrict__ adj,
                                                  const int* __restrict__ offs,
                                                  const float* __restrict__ dinv,
                                                  const float* __restrict__ bias,
                                                  float* __restrict__ hout, int n) {
    int wave = (int)((blockIdx.x * (size_t)blockDim.x + threadIdx.x) >> 6);
    int lane = threadIdx.x & 63;
    if (wave >= n) return;
    int i = wave;
    int half = lane >> 5;        // 0 or 1
    int sl = lane & 31;          // uint2 index within row (cols 4sl..4sl+3)
    const uint2* xw2 = (const uint2*)xwb;    // row stride = 32 uint2

    float a0 = 0.f, a1 = 0.f, a2 = 0.f, a3 = 0.f;

    int s = offs[i], e = offs[i + 1];
    int deg = e - s;
    int total = deg + 1;         // + self (virtual edge v == deg)
    int v = 0;

    // main: 16 virtual edges per iteration = 8 uint2 loads in flight
    for (; v + 16 <= total; v += 16) {
        int r[16];
#pragma unroll
        for (int k = 0; k < 16; k++) {
            int vv = v + k;
            r[k] = (vv < deg) ? adj[s + vv] : i;   // uniform compare, scalar load
        }
        uint2 u0 = xw2[(size_t)(half ? r[1]  : r[0])  * 32 + sl];
        uint2 u1 = xw2[(size_t)(half ? r[3]  : r[2])  * 32 + sl];
        uint2 u2 = xw2[(size_t)(half ? r[5]  : r[4])  * 32 + sl];
        uint2 u3 = xw2[(size_t)(half ? r[7]  : r[6])  * 32 + sl];
        uint2 u4 = xw2[(size_t)(half ? r[9]  : r[8])  * 32 + sl];
        uint2 u5 = xw2[(size_t)(half ? r[11] : r[10]) * 32 + sl];
        uint2 u6 = xw2[(size_t)(half ? r[13] : r[12]) * 32 + sl];
        uint2 u7 = xw2[(size_t)(half ? r[15] : r[14]) * 32 + sl];
        a0 += bf_lo(u0.x); a1 += bf_hi(u0.x); a2 += bf_lo(u0.y); a3 += bf_hi(u0.y);
        a0 += bf_lo(u1.x); a1 += bf_hi(u1.x); a2 += bf_lo(u1.y); a3 += bf_hi(u1.y);
        a0 += bf_lo(u2.x); a1 += bf_hi(u2.x); a2 += bf_lo(u2.y); a3 += bf_hi(u2.y);
        a0 += bf_lo(u3.x); a1 += bf_hi(u3.x); a2 += bf_lo(u3.y); a3 += bf_hi(u3.y);
        a0 += bf_lo(u4.x); a1 += bf_hi(u4.x); a2 += bf_lo(u4.y); a3 += bf_hi(u4.y);
        a0 += bf_lo(u5.x); a1 += bf_hi(u5.x); a2 += bf_lo(u5.y); a3 += bf_hi(u5.y);
        a0 += bf_lo(u6.x); a1 += bf_hi(u6.x); a2 += bf_lo(u6.y); a3 += bf_hi(u6.y);
        a0 += bf_lo(u7.x); a1 += bf_hi(u7.x); a2 += bf_lo(u7.y); a3 += bf_hi(u7.y);
    }
    // mid: 8 virtual edges = 4 loads
    for (; v + 8 <= total; v += 8) {
        int r[8];
#pragma unroll
        for (int k = 0; k < 8; k++) {
            int vv = v + k;
            r[k] = (vv < deg) ? adj[s + vv] : i;
        }
        uint2 u0 = xw2[(size_t)(half ? r[1] : r[0]) * 32 + sl];
        uint2 u1 = xw2[(size_t)(half ? r[3] : r[2]) * 32 + sl];
        uint2 u2 = xw2[(size_t)(half ? r[5] : r[4]) * 32 + sl];
        uint2 u3 = xw2[(size_t)(half ? r[7] : r[6]) * 32 + sl];
        a0 += bf_lo(u0.x); a1 += bf_hi(u0.x); a2 += bf_lo(u0.y); a3 += bf_hi(u0.y);
        a0 += bf_lo(u1.x); a1 += bf_hi(u1.x); a2 += bf_lo(u1.y); a3 += bf_hi(u1.y);
        a0 += bf_lo(u2.x); a1 += bf_hi(u2.x); a2 += bf_lo(u2.y); a3 += bf_hi(u2.y);
        a0 += bf_lo(u3.x); a1 += bf_hi(u3.x); a2 += bf_lo(u3.y); a3 += bf_hi(u3.y);
    }
    // tail: pairs (with validity gating for odd remainder)
    for (; v < total; v += 2) {
        int ra = (v < deg) ? adj[s + v] : i;
        bool bval = (v + 1 < total);
        int rb = bval ? ((v + 1 < deg) ? adj[s + v + 1] : i) : i;
        uint2 u = xw2[(size_t)(half ? rb : ra) * 32 + sl];
        if (half == 0 || bval) {
            a0 += bf_lo(u.x); a1 += bf_hi(u.x);
            a2 += bf_lo(u.y); a3 += bf_hi(u.y);
        }
    }

    // combine halves (4 shuffles only)
    a0 += __shfl_xor(a0, 32, 64);
    a1 += __shfl_xor(a1, 32, 64);
    a2 += __shfl_xor(a2, 32, 64);
    a3 += __shfl_xor(a3, 32, 64);

    if (half == 0) {
        float di = dinv[i];
        float4 bv = ((const float4*)bias)[sl];
        float4 o;
        o.x = fmaxf(fmaf(di, a0, bv.x), 0.f);
        o.y = fmaxf(fmaf(di, a1, bv.y), 0.f);
        o.z = fmaxf(fmaf(di, a2, bv.z), 0.f);
        o.w = fmaxf(fmaf(di, a3, bv.w), 0.f);
        ((float4*)(hout + (size_t)i * D))[sl] = o;
    }
}

// ---------------- edge-classifier precompute ----------------

__global__ __launch_bounds__(256) void pq_kernel(const float* __restrict__ h,
                                                 const float* __restrict__ Wfc,
                                                 const float* __restrict__ bfc,
                                                 float* __restrict__ P1,
                                                 float* __restrict__ P2, int n) {
    int i = blockIdx.x * blockDim.x + threadIdx.x;
    if (i >= n) return;
    const float4* hr = (const float4*)(h + (size_t)i * D);
    const float4* W4 = (const float4*)Wfc;
    float p0 = bfc[0], p1 = bfc[1], p2 = bfc[2], p3 = bfc[3];
    float q0 = 0.f, q1 = 0.f, q2 = 0.f, q3 = 0.f;
#pragma unroll 8
    for (int kk = 0; kk < 32; kk++) {
        float4 f = hr[kk];
#pragma unroll
        for (int j = 0; j < 4; j++) {
            float fv = (j == 0) ? f.x : (j == 1) ? f.y : (j == 2) ? f.z : f.w;
            int k = kk * 4 + j;
            float4 w1 = W4[k];
            float4 w2 = W4[128 + k];
            p0 = fmaf(fv, w1.x, p0); p1 = fmaf(fv, w1.y, p1);
            p2 = fmaf(fv, w1.z, p2); p3 = fmaf(fv, w1.w, p3);
            q0 = fmaf(fv, w2.x, q0); q1 = fmaf(fv, w2.y, q1);
            q2 = fmaf(fv, w2.z, q2); q3 = fmaf(fv, w2.w, q3);
        }
    }
    ((float4*)P1)[i] = make_float4(p0, p1, p2, p3);
    ((float4*)P2)[i] = make_float4(q0, q1, q2, q3);
}

// ---------------- edge classifier: one THREAD per edge ----------------

__global__ __launch_bounds__(256) void edge2_kernel(const int* __restrict__ row,
                                                    const int* __restrict__ col,
                                                    const float* __restrict__ P1,
                                                    const float* __restrict__ P2,
                                                    float* __restrict__ out, int E) {
    int e = blockIdx.x * blockDim.x + threadIdx.x;
    if (e >= E) return;
    int r = row[e], c = col[e];
    float4 a = ((const float4*)P1)[r];
    float4 b = ((const float4*)P2)[c];
    float sx = a.x + b.x, sy = a.y + b.y, sz = a.z + b.z, sw = a.w + b.w;
    float m = fmaxf(fmaxf(sx, sy), fmaxf(sz, sw));
    float e0 = expf(sx - m), e1 = expf(sy - m), e2 = expf(sz - m), e3 = expf(sw - m);
    float lse = m + logf(e0 + e1 + e2 + e3);
    *(float4*)(out + (size_t)e * 4) = make_float4(sx - lse, sy - lse, sz - lse, sw - lse);
}

// ---------------- launch ----------------

extern "C" void kernel_launch(void* const* d_in, const int* in_sizes, int n_in,
                              void* d_out, int out_size, void* d_ws, size_t ws_size,
                              hipStream_t stream) {
    const float* x   = (const float*)d_in[0];
    const int*   ei  = (const int*)d_in[1];
    const float* W1  = (const float*)d_in[2];
    const float* b1  = (const float*)d_in[3];
    const float* W2  = (const float*)d_in[4];
    const float* b2  = (const float*)d_in[5];
    const float* Wfc = (const float*)d_in[6];
    const float* bfc = (const float*)d_in[7];
    float* out = (float*)d_out;

    int n = in_sizes[0] / D;        // 50000
    int E = in_sizes[1] / 2;        // 600000
    const int* row = ei;            // edge_index[0]
    const int* col = ei + E;        // edge_index[1]
    int nbScan = (n + SCAN_CHUNK - 1) / SCAN_CHUNK;   // 25

    // workspace layout (all segments 16B-aligned)
    uint16_t* xwb  = (uint16_t*)d_ws;                    // n*D bf16 (dinv-prescaled xW)
    float*    h    = (float*)(xwb + (size_t)n * D);      // n*D f32
    int*      cnt  = (int*)(h + (size_t)n * D);          // n   } adjacent: one memset
    int*      curs = cnt + n;                            // n   }
    int*      offs = curs + n;                           // n+4
    int*      bsum = offs + (n + 4);                     // 64
    int*      adj  = bsum + 64;                          // E
    float*    dinv = (float*)(adj + E);                  // n
    uint16_t* Wph  = (uint16_t*)(dinv + n);              // 2*16384 (layer-major)
    uint16_t* Wpl  = Wph + 2 * 16384;                    // 2*16384
    float*    P1   = (float*)(Wpl + 2 * 16384);          // n*4
    float*    P2   = P1 + (size_t)n * 4;                 // n*4

    int nb_n = (n + 255) / 256;
    int nb_e = (E + 255) / 256;

    // CSR build (r7 structure)
    hipMemsetAsync(cnt, 0, (size_t)2 * n * sizeof(int), stream);   // cnt + curs
    countpack_kernel<<<nb_e, 256, 0, stream>>>(col, cnt, E, W1, W2, Wph, Wpl);
    scanA_kernel<<<nbScan, 256, 0, stream>>>(cnt, bsum, dinv, n);
    scanC_kernel<<<nbScan, 256, 0, stream>>>(cnt, bsum, offs, n, nbScan);
    fill_kernel<<<nb_e, 256, 0, stream>>>(row, col, offs, curs, adj, E);

    int nbG = (n + 63) / 64;

    // layer 1
    gemm_mfma_kernel<<<nbG, 256, 0, stream>>>(x, Wph, Wpl, dinv, xwb, n);
    agg_kernel<<<(n + 3) / 4, 256, 0, stream>>>(xwb, adj, offs, dinv, b1, h, n);
    // layer 2
    gemm_mfma_kernel<<<nbG, 256, 0, stream>>>(h, Wph + 16384, Wpl + 16384, dinv, xwb, n);
    agg_kernel<<<(n + 3) / 4, 256, 0, stream>>>(xwb, adj, offs, dinv, b2, h, n);

    // edge classifier
    pq_kernel<<<nb_n, 256, 0, stream>>>(h, Wfc, bfc, P1, P2, n);
    edge2_kernel<<<nb_e, 256, 0, stream>>>(row, col, P1, P2, out, E);
}